// Round 3
// baseline (3823.403 us; speedup 1.0000x reference)
//
#include <hip/hip_runtime.h>
#include <math.h>

#define B 32
#define S 256
#define H 768
#define V 30522
#define NU 5
#define MV 4
#define NEG_INF -10000.0f

// logits GEMM tiling
#define VP 30720      // padded V stride for partials
#define NT 239        // ceil(V/128) v-tiles
#define VT 128        // v per tile
#define KSPLIT 4
#define KCH 192       // 768 / KSPLIT
#define KT 32         // k per LDS phase

__device__ __forceinline__ float sigm(float x){ return 1.0f/(1.0f + expf(-x)); }

// ---------------- GRU: h_new = GRUCell(w, h), writes h and h-transposed --------
__global__ __launch_bounds__(256) void gru_kernel(
    const float* __restrict__ wp, int wstride,
    const float* __restrict__ hin, float* __restrict__ hout,
    float* __restrict__ htr,
    const float* __restrict__ Wih, const float* __restrict__ Whh,
    const float* __restrict__ bih, const float* __restrict__ bhh)
{
    int wid  = blockIdx.x * 4 + (threadIdx.x >> 6);
    int lane = threadIdx.x & 63;
    int j  = wid >> 2;     // [0,768)
    int bg = wid & 3;      // [0,4)

    float aI0[8], aI1[8], aI2[8], aH0[8], aH1[8], aH2[8];
#pragma unroll
    for (int bb = 0; bb < 8; bb++){ aI0[bb]=aI1[bb]=aI2[bb]=aH0[bb]=aH1[bb]=aH2[bb]=0.f; }

#pragma unroll
    for (int it = 0; it < 3; it++){
        int k = it*256 + lane*4;
        float4 w0 = *(const float4*)(Wih + (size_t)(0*H + j)*H + k);
        float4 w1 = *(const float4*)(Wih + (size_t)(1*H + j)*H + k);
        float4 w2 = *(const float4*)(Wih + (size_t)(2*H + j)*H + k);
        float4 u0 = *(const float4*)(Whh + (size_t)(0*H + j)*H + k);
        float4 u1 = *(const float4*)(Whh + (size_t)(1*H + j)*H + k);
        float4 u2 = *(const float4*)(Whh + (size_t)(2*H + j)*H + k);
#pragma unroll
        for (int bb = 0; bb < 8; bb++){
            int b = bg*8 + bb;
            float4 x = *(const float4*)(wp  + (size_t)b*wstride + k);
            float4 h = *(const float4*)(hin + (size_t)b*H + k);
            aI0[bb] += w0.x*x.x + w0.y*x.y + w0.z*x.z + w0.w*x.w;
            aI1[bb] += w1.x*x.x + w1.y*x.y + w1.z*x.z + w1.w*x.w;
            aI2[bb] += w2.x*x.x + w2.y*x.y + w2.z*x.z + w2.w*x.w;
            aH0[bb] += u0.x*h.x + u0.y*h.y + u0.z*h.z + u0.w*h.w;
            aH1[bb] += u1.x*h.x + u1.y*h.y + u1.z*h.z + u1.w*h.w;
            aH2[bb] += u2.x*h.x + u2.y*h.y + u2.z*h.z + u2.w*h.w;
        }
    }
    float rRZ0[8], rRZ1[8], rIN[8], rHN[8];
#pragma unroll
    for (int bb = 0; bb < 8; bb++){
        rRZ0[bb] = aI0[bb] + aH0[bb];
        rRZ1[bb] = aI1[bb] + aH1[bb];
        rIN[bb]  = aI2[bb];
        rHN[bb]  = aH2[bb];
    }
#pragma unroll
    for (int bb = 0; bb < 8; bb++){
#pragma unroll
        for (int m = 32; m >= 1; m >>= 1){
            rRZ0[bb] += __shfl_xor(rRZ0[bb], m, 64);
            rRZ1[bb] += __shfl_xor(rRZ1[bb], m, 64);
            rIN[bb]  += __shfl_xor(rIN[bb],  m, 64);
            rHN[bb]  += __shfl_xor(rHN[bb],  m, 64);
        }
    }
    if (lane == 0){
        float brz0 = bih[j]     + bhh[j];
        float brz1 = bih[H+j]   + bhh[H+j];
        float bin_ = bih[2*H+j];
        float bhn_ = bhh[2*H+j];
#pragma unroll
        for (int bb = 0; bb < 8; bb++){
            int b = bg*8 + bb;
            float r = sigm(rRZ0[bb] + brz0);
            float z = sigm(rRZ1[bb] + brz1);
            float n = tanhf(rIN[bb] + bin_ + r*(rHN[bb] + bhn_));
            float ho = hin[(size_t)b*H + j];
            float hv = (1.0f - z)*n + z*ho;
            hout[(size_t)b*H + j] = hv;
            htr[(size_t)j*32 + b] = hv;
        }
    }
}

// ---------------- attn_e[b,s] = enc[b,s,:] . h[b,:] ----------------------------
__global__ __launch_bounds__(256) void attn_e_kernel(
    const float* __restrict__ hb, const float* __restrict__ enc,
    float* __restrict__ attnE)
{
    int wid  = blockIdx.x * 4 + (threadIdx.x >> 6);
    int lane = threadIdx.x & 63;
    int b = wid >> 8;
    int s = wid & 255;
    const float* er = enc + ((size_t)b*S + s)*H;
    const float* hr = hb + (size_t)b*H;
    float acc = 0.f;
#pragma unroll
    for (int it = 0; it < 3; it++){
        int k = it*256 + lane*4;
        float4 e4 = *(const float4*)(er + k);
        float4 h4 = *(const float4*)(hr + k);
        acc += e4.x*h4.x + e4.y*h4.y + e4.z*h4.z + e4.w*h4.w;
    }
#pragma unroll
    for (int m = 32; m >= 1; m >>= 1) acc += __shfl_xor(acc, m, 64);
    if (lane == 0) attnE[b*S + s] = acc;
}

// ------- masked softmax over S (redundant per k-chunk) + context chunk ---------
__global__ __launch_bounds__(256) void ctx_kernel(
    const float* __restrict__ attnE, const int* __restrict__ ids,
    const float* __restrict__ enc, float* __restrict__ attnH,
    float* __restrict__ ctx)
{
    __shared__ float ah[S];
    __shared__ float red[S];
    int b  = blockIdx.x / 3;
    int kc = blockIdx.x % 3;
    int t  = threadIdx.x;

    float e = attnE[b*S + t];
    if (ids[b*S + t] == 0) e = NEG_INF;
    red[t] = e; __syncthreads();
    for (int s = 128; s > 0; s >>= 1){ if (t < s) red[t] = fmaxf(red[t], red[t+s]); __syncthreads(); }
    float mx = red[0]; __syncthreads();
    float p = expf(e - mx);
    red[t] = p; __syncthreads();
    for (int s = 128; s > 0; s >>= 1){ if (t < s) red[t] += red[t+s]; __syncthreads(); }
    float a = p / red[0];
    ah[t] = a;
    if (kc == 0) attnH[b*S + t] = a;
    __syncthreads();

    int k = kc*256 + t;
    const float* ep = enc + (size_t)b*S*H + k;
    float acc = 0.f;
#pragma unroll 4
    for (int s = 0; s < S; s++) acc += ah[s] * ep[(size_t)s*H];
    ctx[b*H + k] = acc;
}

// ---------------- logits partial GEMM: 128v x 32b tile, K/4 per block ----------
// grid NT*4+1 blocks: [0,NT*4) = (vtile*4 + ksplit); last block = p_gen.
__global__ __launch_bounds__(256) void logits_kernel(
    const float* __restrict__ E, const float* __restrict__ htr,
    float* __restrict__ part,
    const float* __restrict__ hb, const float* __restrict__ wp, int wstride,
    const float* __restrict__ ctx, const float* __restrict__ wgw,
    const float* __restrict__ wgb, float* __restrict__ pgen)
{
    int t = threadIdx.x;

    if (blockIdx.x == NT*4){
        int b = t >> 3, sl = t & 7;
        float s = 0.f;
        for (int i = sl; i < 2304; i += 8){
            float xv;
            if (i < 768)        xv = wp[(size_t)b*wstride + i];
            else if (i < 1536)  xv = hb[b*H + (i - 768)];
            else                xv = ctx[b*H + (i - 1536)];
            s += xv * wgw[i];
        }
#pragma unroll
        for (int m = 4; m >= 1; m >>= 1) s += __shfl_xor(s, m, 8);
        if (sl == 0) pgen[b] = sigm(s + wgb[0]);
        return;
    }

    __shared__ float Ets[KT][VT];    // 16 KB  (read: lane-stride 16B, conflict-free)
    __shared__ float Hs[KCH][32];    // 24 KB  (read: 2 addrs/wave, broadcast)

    int vt = blockIdx.x >> 2;
    int ks = blockIdx.x & 3;
    int v0 = vt * VT;
    int k0 = ks * KCH;

    // stage h chunk [k0,k0+KCH) x 32b  (coalesced f4)
#pragma unroll
    for (int j = 0; j < 6; j++){
        int idx = t + 256*j;  // f4 index in [0,1536)
        float4 hv = *(const float4*)(htr + (size_t)k0*32 + (size_t)idx*4);
        *(float4*)((float*)Hs + (size_t)idx*4) = hv;
    }

    int w  = t >> 6;        // wave -> b base 8w
    int l  = t & 63;
    int vq = l & 31;        // v-quad: v = v0 + 4*vq
    int bh = l >> 5;        // b sub-base: 8w + 4*bh
    int kq = t & 7;         // staging: k-quad
    int sr = t >> 3;        // staging: v row base

    float4 acc[4];
#pragma unroll
    for (int j = 0; j < 4; j++){ acc[j].x=0.f; acc[j].y=0.f; acc[j].z=0.f; acc[j].w=0.f; }

    for (int ph = 0; ph < KCH/KT; ph++){
        int kb = k0 + ph*KT;
        __syncthreads();
#pragma unroll
        for (int i = 0; i < 4; i++){
            int v = sr + 32*i;                 // [0,128)
            int vr = v0 + v; if (vr >= V) vr = V-1;
            float4 e4 = *(const float4*)(E + (size_t)vr*H + kb + 4*kq);
            Ets[4*kq+0][v] = e4.x;
            Ets[4*kq+1][v] = e4.y;
            Ets[4*kq+2][v] = e4.z;
            Ets[4*kq+3][v] = e4.w;
        }
        __syncthreads();
        int hbase = 8*w + 4*bh;
#pragma unroll 4
        for (int k = 0; k < KT; k++){
            float4 e4 = *(const float4*)(&Ets[k][4*vq]);
            float4 h4 = *(const float4*)(&Hs[ph*KT + k][hbase]);
            acc[0].x += h4.x*e4.x; acc[0].y += h4.x*e4.y; acc[0].z += h4.x*e4.z; acc[0].w += h4.x*e4.w;
            acc[1].x += h4.y*e4.x; acc[1].y += h4.y*e4.y; acc[1].z += h4.y*e4.z; acc[1].w += h4.y*e4.w;
            acc[2].x += h4.z*e4.x; acc[2].y += h4.z*e4.y; acc[2].z += h4.z*e4.z; acc[2].w += h4.z*e4.w;
            acc[3].x += h4.w*e4.x; acc[3].y += h4.w*e4.y; acc[3].z += h4.w*e4.z; acc[3].w += h4.w*e4.w;
        }
    }
    float* pp = part + (size_t)ks*32*VP;
    int v = v0 + 4*vq;
#pragma unroll
    for (int j = 0; j < 4; j++){
        int b = 8*w + 4*bh + j;
        *(float4*)(pp + (size_t)b*VP + v) = acc[j];
    }
}

// ------- fused: sum partials -> softmax -> *pgen -> write out -> scatter -> argmax
__global__ __launch_bounds__(1024) void softmax_fused_kernel(
    const float* __restrict__ part, const float* __restrict__ pgen,
    const float* __restrict__ attnH, const int* __restrict__ ids,
    float* __restrict__ out, const float* __restrict__ E,
    float* __restrict__ wbuf, int u, int mm)
{
    __shared__ float red[1024];
    __shared__ int   ri[1024];
    int b = blockIdx.x, t = threadIdx.x;

    float r[30];
    float mx = -INFINITY;
#pragma unroll
    for (int i = 0; i < 30; i++){
        int v = t + 1024*i;
        float x = -INFINITY;
        if (v < V){
            x = part[(size_t)b*VP + v]
              + part[(size_t)(32+b)*VP + v]
              + part[(size_t)(64+b)*VP + v]
              + part[(size_t)(96+b)*VP + v];
        }
        r[i] = x;
        mx = fmaxf(mx, x);
    }
    red[t] = mx; __syncthreads();
    for (int s = 512; s > 0; s >>= 1){ if (t < s) red[t] = fmaxf(red[t], red[t+s]); __syncthreads(); }
    mx = red[0]; __syncthreads();

    float sm = 0.f;
#pragma unroll
    for (int i = 0; i < 30; i++){
        if (t + 1024*i < V) sm += expf(r[i] - mx);
    }
    red[t] = sm; __syncthreads();
    for (int s = 512; s > 0; s >>= 1){ if (t < s) red[t] += red[t+s]; __syncthreads(); }
    float sum = red[0]; __syncthreads();

    float pg  = pgen[b];
    float scl = pg / sum;
    float* orow = out + (((size_t)b*NU + u)*MV + mm)*(size_t)V;
#pragma unroll
    for (int i = 0; i < 30; i++){
        int v = t + 1024*i;
        if (v < V) orow[v] = expf(r[i] - mx) * scl;
    }
    __threadfence();       // writes visible at L2 before same-row atomics
    __syncthreads();
    if (t < S){
        int id = ids[b*S + t];
        atomicAdd(orow + id, (1.0f - pg) * attnH[b*S + t]);
    }
    __threadfence();       // invalidate L1 so re-reads see atomic results
    __syncthreads();

    float bv = -INFINITY; int bi = 0;
#pragma unroll
    for (int i = 0; i < 30; i++){
        int v = t + 1024*i;
        if (v < V){
            float x = orow[v];
            if (x > bv){ bv = x; bi = v; }
        }
    }
    red[t] = bv; ri[t] = bi; __syncthreads();
    for (int s = 512; s > 0; s >>= 1){
        if (t < s){
            if (red[t+s] > red[t] || (red[t+s] == red[t] && ri[t+s] < ri[t])){
                red[t] = red[t+s]; ri[t] = ri[t+s];
            }
        }
        __syncthreads();
    }
    int idx = ri[0];
    for (int k = t; k < H; k += 1024) wbuf[b*H + k] = E[(size_t)idx*H + k];
}

extern "C" void kernel_launch(void* const* d_in, const int* in_sizes, int n_in,
                              void* d_out, int out_size, void* d_ws, size_t ws_size,
                              hipStream_t stream)
{
    const int*   ids = (const int*)  d_in[0];
    const float* dec = (const float*)d_in[1];
    const float* enc = (const float*)d_in[2];
    const float* hid = (const float*)d_in[3];
    const float* E   = (const float*)d_in[4];
    const float* Wih = (const float*)d_in[5];
    const float* Whh = (const float*)d_in[6];
    const float* bih = (const float*)d_in[7];
    const float* bhh = (const float*)d_in[8];
    const float* wgw = (const float*)d_in[9];
    const float* wgb = (const float*)d_in[10];
    float* out = (float*)d_out;
    float* ws  = (float*)d_ws;

    float* wbuf    = ws;                 // 24576
    float* hb0     = ws + 24576;         // 24576
    float* hb1     = ws + 49152;         // 24576
    float* ctxb    = ws + 73728;         // 24576
    float* attnE   = ws + 98304;         // 8192
    float* attnH   = ws + 106496;        // 8192
    float* htr     = ws + 114688;        // 24576 (h transposed [768][32])
    float* pgenb   = ws + 139264;        // 32
    float* part    = ws + 139360;        // 4*32*30720 floats

    for (int u = 0; u < NU; u++){
        for (int mm = 0; mm < MV; mm++){
            int st = u*MV + mm;
            const float* wp; int wstride;
            if (mm == 0){ wp = dec + (size_t)u*H; wstride = NU*H; }
            else        { wp = wbuf;              wstride = H; }
            const float* hin = (st == 0) ? hid : ((st & 1) ? hb0 : hb1);
            float*      hout = (st & 1) ? hb1 : hb0;

            gru_kernel<<<768, 256, 0, stream>>>(wp, wstride, hin, hout, htr, Wih, Whh, bih, bhh);
            attn_e_kernel<<<2048, 256, 0, stream>>>(hout, enc, attnE);
            ctx_kernel<<<96, 256, 0, stream>>>(attnE, ids, enc, attnH, ctxb);
            logits_kernel<<<NT*4+1, 256, 0, stream>>>(E, htr, part, hout, wp, wstride, ctxb, wgw, wgb, pgenb);
            softmax_fused_kernel<<<32, 1024, 0, stream>>>(part, pgenb, attnH, ids, out, E, wbuf, u, mm);
        }
    }
}